// Round 1
// baseline (260.613 us; speedup 1.0000x reference)
//
#include <hip/hip_runtime.h>
#include <hip/hip_fp16.h>

#define P_PLANE (1080*1920)          // 2,073,600 pixels per channel plane
#define LUT_C   35937                 // 33*33*33, per-channel LUT stride
#define N_IMG   4

// ---------------------------------------------------------------------------
// Preprocess: rebuild LUT as cell-duplicated fp16 table.
// Cell (bid,gid,rid) in [0,32)^3 -> 64 bytes: 8 corners x (r,g,b,pad) halves.
// Corner k = db*4 + dg*2 + dr. Total 32768 cells * 64B = 2 MB.
// ---------------------------------------------------------------------------
__global__ __launch_bounds__(256) void build_table(const float* __restrict__ lut,
                                                   uint4* __restrict__ T) {
    int cell = blockIdx.x * blockDim.x + threadIdx.x;   // 0 .. 32767
    int rid = cell & 31;
    int gid = (cell >> 5) & 31;
    int bid = cell >> 10;
    const float* b0 = lut + bid * 1089 + gid * 33 + rid;
    uint4 q[4];
    __half* h = (__half*)q;
#pragma unroll
    for (int k = 0; k < 8; ++k) {
        int off = (k >> 2) * 1089 + ((k >> 1) & 1) * 33 + (k & 1);
        h[k * 4 + 0] = __float2half(b0[off]);
        h[k * 4 + 1] = __float2half(b0[LUT_C + off]);
        h[k * 4 + 2] = __float2half(b0[2 * LUT_C + off]);
        h[k * 4 + 3] = __float2half(0.0f);
    }
    uint4* dst = T + (size_t)cell * 4;
    dst[0] = q[0]; dst[1] = q[1]; dst[2] = q[2]; dst[3] = q[3];
}

// Accumulate one 16B chunk = 2 corners (dr=0 with weight wA, dr=1 with wB).
__device__ __forceinline__ void acc_chunk(const uint4& q, float wA, float wB,
                                          float& aR, float& aG, float& aB) {
    const __half* h = (const __half*)&q;
    aR = fmaf(wA, __half2float(h[0]), fmaf(wB, __half2float(h[4]), aR));
    aG = fmaf(wA, __half2float(h[1]), fmaf(wB, __half2float(h[5]), aG));
    aB = fmaf(wA, __half2float(h[2]), fmaf(wB, __half2float(h[6]), aB));
}

// ---------------------------------------------------------------------------
// Main kernel: 4 pixels per thread (float4 I/O), 4 dwordx4 gathers per pixel
// (one 64B cache line per pixel) from the fp16 cell table.
// ---------------------------------------------------------------------------
__global__ __launch_bounds__(256) void apply_lut(const float* __restrict__ x,
                                                 const __half* __restrict__ T,
                                                 float* __restrict__ out) {
    const float inv = (float)(1.0 / (1.000001 / 32.0));   // matches reference f32 rounding
    int n  = blockIdx.y;
    int i4 = blockIdx.x * blockDim.x + threadIdx.x;       // float4-group within plane
    size_t base = (size_t)n * 3 * P_PLANE + (size_t)i4 * 4;

    float4 r4 = *(const float4*)(x + base);
    float4 g4 = *(const float4*)(x + base + P_PLANE);
    float4 b4 = *(const float4*)(x + base + 2 * P_PLANE);

    float r[4] = {r4.x, r4.y, r4.z, r4.w};
    float g[4] = {g4.x, g4.y, g4.z, g4.w};
    float b[4] = {b4.x, b4.y, b4.z, b4.w};
    float oR[4], oG[4], oB[4];

#pragma unroll
    for (int i = 0; i < 4; ++i) {
        float tr = r[i] * inv;
        float tg = g[i] * inv;
        float tb = b[i] * inv;
        float fr_ = floorf(tr), fg_ = floorf(tg), fb_ = floorf(tb);
        float fr = tr - fr_, fg = tg - fg_, fb = tb - fb_;   // fracs BEFORE clip (ref semantics)
        int ri = min(max((int)fr_, 0), 31);
        int gi = min(max((int)fg_, 0), 31);
        int bi = min(max((int)fb_, 0), 31);

        const uint4* cp = (const uint4*)(T + ((size_t)(((bi << 5) | gi) << 5 | ri) << 5));
        uint4 q0 = cp[0], q1 = cp[1], q2 = cp[2], q3 = cp[3];

        float wr1 = fr, wr0 = 1.0f - fr;
        float wg1 = fg, wg0 = 1.0f - fg;
        float wb1 = fb, wb0 = 1.0f - fb;
        float w00 = wb0 * wg0, w01 = wb0 * wg1, w10 = wb1 * wg0, w11 = wb1 * wg1;

        float aR = 0.f, aG = 0.f, aB = 0.f;
        acc_chunk(q0, w00 * wr0, w00 * wr1, aR, aG, aB);   // corners (0,0,0),(0,0,1)
        acc_chunk(q1, w01 * wr0, w01 * wr1, aR, aG, aB);   // corners (0,1,0),(0,1,1)
        acc_chunk(q2, w10 * wr0, w10 * wr1, aR, aG, aB);   // corners (1,0,0),(1,0,1)
        acc_chunk(q3, w11 * wr0, w11 * wr1, aR, aG, aB);   // corners (1,1,0),(1,1,1)

        oR[i] = aR; oG[i] = aG; oB[i] = aB;
    }

    *(float4*)(out + base)               = make_float4(oR[0], oR[1], oR[2], oR[3]);
    *(float4*)(out + base + P_PLANE)     = make_float4(oG[0], oG[1], oG[2], oG[3]);
    *(float4*)(out + base + 2 * P_PLANE) = make_float4(oB[0], oB[1], oB[2], oB[3]);
}

// ---------------------------------------------------------------------------
// Fallback (if ws too small): direct fp32 gathers from original LUT layout.
// ---------------------------------------------------------------------------
__global__ __launch_bounds__(256) void apply_lut_direct(const float* __restrict__ x,
                                                        const float* __restrict__ lut,
                                                        float* __restrict__ out) {
    const float inv = (float)(1.0 / (1.000001 / 32.0));
    int p = blockIdx.x * blockDim.x + threadIdx.x;
    int n = blockIdx.y;
    if (p >= P_PLANE) return;
    size_t base = (size_t)n * 3 * P_PLANE + p;
    float r = x[base], g = x[base + P_PLANE], b = x[base + 2 * P_PLANE];

    float tr = r * inv, tg = g * inv, tb = b * inv;
    float fr_ = floorf(tr), fg_ = floorf(tg), fb_ = floorf(tb);
    float fr = tr - fr_, fg = tg - fg_, fb = tb - fb_;
    int ri = min(max((int)fr_, 0), 31);
    int gi = min(max((int)fg_, 0), 31);
    int bi = min(max((int)fb_, 0), 31);

    float wr[2] = {1.0f - fr, fr};
    float wg[2] = {1.0f - fg, fg};
    float wb[2] = {1.0f - fb, fb};

    float acc[3] = {0.f, 0.f, 0.f};
    int cbase = bi * 1089 + gi * 33 + ri;
#pragma unroll
    for (int c = 0; c < 3; ++c) {
        const float* L = lut + c * LUT_C + cbase;
        float a = 0.f;
#pragma unroll
        for (int k = 0; k < 8; ++k) {
            int db = k >> 2, dg = (k >> 1) & 1, dr = k & 1;
            float w = wb[db] * wg[dg] * wr[dr];
            a = fmaf(w, L[db * 1089 + dg * 33 + dr], a);
        }
        acc[c] = a;
    }
    out[base]               = acc[0];
    out[base + P_PLANE]     = acc[1];
    out[base + 2 * P_PLANE] = acc[2];
}

extern "C" void kernel_launch(void* const* d_in, const int* in_sizes, int n_in,
                              void* d_out, int out_size, void* d_ws, size_t ws_size,
                              hipStream_t stream) {
    const float* lut = (const float*)d_in[0];
    const float* x   = (const float*)d_in[1];
    float* out = (float*)d_out;

    const size_t table_bytes = (size_t)32768 * 64;   // 2 MB
    if (ws_size >= table_bytes) {
        __half* T = (__half*)d_ws;
        build_table<<<128, 256, 0, stream>>>(lut, (uint4*)T);
        // P_PLANE / 4 pixels-per-thread / 256 threads = 2025 blocks per image
        apply_lut<<<dim3(P_PLANE / (4 * 256), N_IMG), 256, 0, stream>>>(x, T, out);
    } else {
        apply_lut_direct<<<dim3((P_PLANE + 255) / 256, N_IMG), 256, 0, stream>>>(x, lut, out);
    }
}

// Round 3
// 187.523 us; speedup vs baseline: 1.3898x; 1.3898x over previous
//
#include <hip/hip_runtime.h>
#include <hip/hip_fp16.h>

#define P_PLANE (1080*1920)          // 2,073,600 pixels per channel plane
#define LUT_C   35937                 // 33*33*33, per-channel LUT stride
#define N_IMG   4
#define SMEM_WORDS 35937
#define SMEM_BYTES (SMEM_WORDS * 4)   // 143,748 B of LDS

typedef float fvec4 __attribute__((ext_vector_type(4)));   // builtin-compatible float4

// ---------------------------------------------------------------------------
// Build linear u8 table in ws: entry i (= b*1089+g*33+r) packs (r,g,b,0) u8.
// 35937 entries * 4B = 140.4 KB. Quantization err <= 1/510 ~ 2e-3.
// ---------------------------------------------------------------------------
__global__ __launch_bounds__(256) void build_lin_u8(const float* __restrict__ lut,
                                                    unsigned int* __restrict__ T) {
    int i = blockIdx.x * blockDim.x + threadIdx.x;
    if (i >= LUT_C) return;
    unsigned int r = (unsigned int)__float2int_rn(lut[i] * 255.0f);
    unsigned int g = (unsigned int)__float2int_rn(lut[LUT_C + i] * 255.0f);
    unsigned int b = (unsigned int)__float2int_rn(lut[2 * LUT_C + i] * 255.0f);
    T[i] = r | (g << 8) | (b << 16);
}

__device__ __forceinline__ float ub0(unsigned int e) { return (float)(e & 255u); }
__device__ __forceinline__ float ub1(unsigned int e) { return (float)((e >> 8) & 255u); }
__device__ __forceinline__ float ub2(unsigned int e) { return (float)((e >> 16) & 255u); }

// ---------------------------------------------------------------------------
// Main kernel: full LUT (u8x4) resident in LDS; 8 scattered LDS dword reads
// per pixel; float4 streaming I/O; nontemporal output stores.
// ---------------------------------------------------------------------------
__global__ __launch_bounds__(1024) void apply_lut_lds(const float* __restrict__ x,
                                                      const unsigned int* __restrict__ T,
                                                      float* __restrict__ out) {
    extern __shared__ unsigned int s_lut[];
    const int tid = threadIdx.x;

    // Fill LDS: 8984 uint4 + 1 tail word, coalesced.
    {
        const uint4* Tv = (const uint4*)T;
        uint4* sv = (uint4*)s_lut;
        for (int i = tid; i < SMEM_WORDS / 4; i += blockDim.x) sv[i] = Tv[i];
        if (tid == 0) s_lut[SMEM_WORDS - 1] = T[SMEM_WORDS - 1];
    }
    __syncthreads();

    const float inv = (float)(1.0 / (1.000001 / 32.0));   // matches reference f32 rounding
    const float qs = 1.0f / 255.0f;                        // u8 dequant, folded into wb
    const int QPI = P_PLANE / 4;                           // 518,400 quads per image
    const int total = N_IMG * QPI;                         // 2,073,600

    for (int q = blockIdx.x * blockDim.x + tid; q < total; q += gridDim.x * blockDim.x) {
        int n  = q / QPI;
        int p4 = q - n * QPI;
        size_t base = (size_t)n * 3 * P_PLANE + (size_t)p4 * 4;

        fvec4 r4 = *(const fvec4*)(x + base);
        fvec4 g4 = *(const fvec4*)(x + base + P_PLANE);
        fvec4 b4 = *(const fvec4*)(x + base + 2 * P_PLANE);

        fvec4 vR, vG, vB;

#pragma unroll
        for (int i = 0; i < 4; ++i) {
            float tr = r4[i] * inv;
            float tg = g4[i] * inv;
            float tb = b4[i] * inv;
            float fr_ = floorf(tr), fg_ = floorf(tg), fb_ = floorf(tb);
            float fr = tr - fr_, fg = tg - fg_, fb = tb - fb_;  // fracs BEFORE clip
            int ri = min(max((int)fr_, 0), 31);
            int gi = min(max((int)fg_, 0), 31);
            int bi = min(max((int)fb_, 0), 31);
            int idx = bi * 1089 + gi * 33 + ri;

            unsigned int e000 = s_lut[idx],        e001 = s_lut[idx + 1];
            unsigned int e010 = s_lut[idx + 33],   e011 = s_lut[idx + 34];
            unsigned int e100 = s_lut[idx + 1089], e101 = s_lut[idx + 1090];
            unsigned int e110 = s_lut[idx + 1122], e111 = s_lut[idx + 1123];

            float wr1 = fr, wr0 = 1.0f - fr;
            float wg1 = fg, wg0 = 1.0f - fg;
            float wb1 = fb * qs, wb0 = (1.0f - fb) * qs;   // fold 1/255 here
            float w00 = wb0 * wg0, w01 = wb0 * wg1, w10 = wb1 * wg0, w11 = wb1 * wg1;
            float w000 = w00 * wr0, w001 = w00 * wr1;
            float w010 = w01 * wr0, w011 = w01 * wr1;
            float w100 = w10 * wr0, w101 = w10 * wr1;
            float w110 = w11 * wr0, w111 = w11 * wr1;

            float aR, aG, aB;
            aR = w000 * ub0(e000);            aG = w000 * ub1(e000);            aB = w000 * ub2(e000);
            aR = fmaf(w001, ub0(e001), aR);   aG = fmaf(w001, ub1(e001), aG);   aB = fmaf(w001, ub2(e001), aB);
            aR = fmaf(w010, ub0(e010), aR);   aG = fmaf(w010, ub1(e010), aG);   aB = fmaf(w010, ub2(e010), aB);
            aR = fmaf(w011, ub0(e011), aR);   aG = fmaf(w011, ub1(e011), aG);   aB = fmaf(w011, ub2(e011), aB);
            aR = fmaf(w100, ub0(e100), aR);   aG = fmaf(w100, ub1(e100), aG);   aB = fmaf(w100, ub2(e100), aB);
            aR = fmaf(w101, ub0(e101), aR);   aG = fmaf(w101, ub1(e101), aG);   aB = fmaf(w101, ub2(e101), aB);
            aR = fmaf(w110, ub0(e110), aR);   aG = fmaf(w110, ub1(e110), aG);   aB = fmaf(w110, ub2(e110), aB);
            aR = fmaf(w111, ub0(e111), aR);   aG = fmaf(w111, ub1(e111), aG);   aB = fmaf(w111, ub2(e111), aB);

            vR[i] = aR; vG[i] = aG; vB[i] = aB;
        }

        __builtin_nontemporal_store(vR, (fvec4*)(out + base));
        __builtin_nontemporal_store(vG, (fvec4*)(out + base + P_PLANE));
        __builtin_nontemporal_store(vB, (fvec4*)(out + base + 2 * P_PLANE));
    }
}

// ===========================================================================
// Fallback path (R0, proven): fp16 cell-duplicated table + global gathers.
// ===========================================================================
__global__ __launch_bounds__(256) void build_table(const float* __restrict__ lut,
                                                   uint4* __restrict__ T) {
    int cell = blockIdx.x * blockDim.x + threadIdx.x;   // 0 .. 32767
    int rid = cell & 31;
    int gid = (cell >> 5) & 31;
    int bid = cell >> 10;
    const float* b0 = lut + bid * 1089 + gid * 33 + rid;
    uint4 q[4];
    __half* h = (__half*)q;
#pragma unroll
    for (int k = 0; k < 8; ++k) {
        int off = (k >> 2) * 1089 + ((k >> 1) & 1) * 33 + (k & 1);
        h[k * 4 + 0] = __float2half(b0[off]);
        h[k * 4 + 1] = __float2half(b0[LUT_C + off]);
        h[k * 4 + 2] = __float2half(b0[2 * LUT_C + off]);
        h[k * 4 + 3] = __float2half(0.0f);
    }
    uint4* dst = T + (size_t)cell * 4;
    dst[0] = q[0]; dst[1] = q[1]; dst[2] = q[2]; dst[3] = q[3];
}

__device__ __forceinline__ void acc_chunk(const uint4& q, float wA, float wB,
                                          float& aR, float& aG, float& aB) {
    const __half* h = (const __half*)&q;
    aR = fmaf(wA, __half2float(h[0]), fmaf(wB, __half2float(h[4]), aR));
    aG = fmaf(wA, __half2float(h[1]), fmaf(wB, __half2float(h[5]), aG));
    aB = fmaf(wA, __half2float(h[2]), fmaf(wB, __half2float(h[6]), aB));
}

__global__ __launch_bounds__(256) void apply_lut(const float* __restrict__ x,
                                                 const __half* __restrict__ T,
                                                 float* __restrict__ out) {
    const float inv = (float)(1.0 / (1.000001 / 32.0));
    int n  = blockIdx.y;
    int i4 = blockIdx.x * blockDim.x + threadIdx.x;
    size_t base = (size_t)n * 3 * P_PLANE + (size_t)i4 * 4;

    float4 r4 = *(const float4*)(x + base);
    float4 g4 = *(const float4*)(x + base + P_PLANE);
    float4 b4 = *(const float4*)(x + base + 2 * P_PLANE);

    float r[4] = {r4.x, r4.y, r4.z, r4.w};
    float g[4] = {g4.x, g4.y, g4.z, g4.w};
    float b[4] = {b4.x, b4.y, b4.z, b4.w};
    float oR[4], oG[4], oB[4];

#pragma unroll
    for (int i = 0; i < 4; ++i) {
        float tr = r[i] * inv;
        float tg = g[i] * inv;
        float tb = b[i] * inv;
        float fr_ = floorf(tr), fg_ = floorf(tg), fb_ = floorf(tb);
        float fr = tr - fr_, fg = tg - fg_, fb = tb - fb_;
        int ri = min(max((int)fr_, 0), 31);
        int gi = min(max((int)fg_, 0), 31);
        int bi = min(max((int)fb_, 0), 31);

        const uint4* cp = (const uint4*)(T + ((size_t)(((bi << 5) | gi) << 5 | ri) << 5));
        uint4 q0 = cp[0], q1 = cp[1], q2 = cp[2], q3 = cp[3];

        float wr1 = fr, wr0 = 1.0f - fr;
        float wg1 = fg, wg0 = 1.0f - fg;
        float wb1 = fb, wb0 = 1.0f - fb;
        float w00 = wb0 * wg0, w01 = wb0 * wg1, w10 = wb1 * wg0, w11 = wb1 * wg1;

        float aR = 0.f, aG = 0.f, aB = 0.f;
        acc_chunk(q0, w00 * wr0, w00 * wr1, aR, aG, aB);
        acc_chunk(q1, w01 * wr0, w01 * wr1, aR, aG, aB);
        acc_chunk(q2, w10 * wr0, w10 * wr1, aR, aG, aB);
        acc_chunk(q3, w11 * wr0, w11 * wr1, aR, aG, aB);

        oR[i] = aR; oG[i] = aG; oB[i] = aB;
    }

    *(float4*)(out + base)               = make_float4(oR[0], oR[1], oR[2], oR[3]);
    *(float4*)(out + base + P_PLANE)     = make_float4(oG[0], oG[1], oG[2], oG[3]);
    *(float4*)(out + base + 2 * P_PLANE) = make_float4(oB[0], oB[1], oB[2], oB[3]);
}

extern "C" void kernel_launch(void* const* d_in, const int* in_sizes, int n_in,
                              void* d_out, int out_size, void* d_ws, size_t ws_size,
                              hipStream_t stream) {
    const float* lut = (const float*)d_in[0];
    const float* x   = (const float*)d_in[1];
    float* out = (float*)d_out;

    // Capture-safe host-side queries (execute immediately, not stream ops).
    int dev = 0;
    (void)hipGetDevice(&dev);
    int max_shm = 0;
    (void)hipDeviceGetAttribute(&max_shm, hipDeviceAttributeMaxSharedMemoryPerBlock, dev);
    // Some runtimes want an explicit opt-in for large dynamic LDS; ignore failure.
    static_assert(SMEM_BYTES == 143748, "lut lds size");
    (void)hipFuncSetAttribute((const void*)apply_lut_lds,
                              hipFuncAttributeMaxDynamicSharedMemorySize, SMEM_BYTES);

    const size_t lin_bytes = (size_t)SMEM_BYTES;
    if (max_shm >= SMEM_BYTES && ws_size >= lin_bytes) {
        unsigned int* T = (unsigned int*)d_ws;
        build_lin_u8<<<(LUT_C + 255) / 256, 256, 0, stream>>>(lut, T);
        // 256 blocks x 1024 threads, 1 block/CU (LDS-bound), grid-stride.
        apply_lut_lds<<<256, 1024, SMEM_BYTES, stream>>>(x, T, out);
    } else {
        const size_t table_bytes = (size_t)32768 * 64;   // 2 MB
        __half* T = (__half*)d_ws;
        build_table<<<128, 256, 0, stream>>>(lut, (uint4*)T);
        apply_lut<<<dim3(P_PLANE / (4 * 256), N_IMG), 256, 0, stream>>>(x, T, out);
    }
}